// Round 12
// baseline (1639.198 us; speedup 1.0000x reference)
//
#include <hip/hip_runtime.h>

// VanillaRNN: h_{t+1} = tanh(W_hx x_t + W_hh h_t + b_h), T=1024, H=512, B=256.
// R12 = R9 (best, 1438 us) + pair-major reduce (hs LDS ring deleted).
// R10 falsified pk_fma (same issue rate as dot2). R11 falsified shfl h-exchange
// (bpermute latency+conflicts > hs ring). R12 removes the hs round-trip a third
// way: lane p of wave w reduces PAIR q=32w+p (rows 2q,2q+1) via 8 float2 reads
// of the UNCHANGED swizzled partial layout (float4 writes already store row
// pairs contiguously). 32 distinct b64 addrs = exactly 2 addrs/bank = 2-way =
// free (m136); upper half-wave duplicates lower (same addr -> broadcast).
// hpack = pack2(tanh(s0),tanh(s1)) forms in the exact lane that next step's
// readlane(p) targets -> no LDS h traffic at all.
// Frozen from R9: k-sliced decomposition (wave w owns k [64w,64w+64), lane owns
// 8 rows in dot phase), W 28 pairs regs + 4 pairs LDS b128, swizzled f32
// partials dbuf, one barrier/step, readlane h-broadcast, asm pin, x_s staging,
// unroll 1, LDS ~104 KB => 1 WG/CU => 2 waves/EU 256-reg budget.

#define T_SEQ    1024
#define HID      512
#define NTHREADS 512
#define NW       8            // waves
#define NCLS     10
#define RP       8            // rows per thread (dot phase)
#define PAIRS    32           // f16 pairs per wave k-slice (64 k)
#define PREG     28           // pairs 0..27 in VGPRs (224 regs)
#define PSTRIDE  576          // padded part row: 512 + 16*4 pad, 16B-aligned

typedef _Float16 half2_t __attribute__((ext_vector_type(2)));

__device__ __forceinline__ unsigned int pack2(float a, float b) {
    half2_t h = {(_Float16)a, (_Float16)b};
    return __builtin_bit_cast(unsigned int, h);
}

__device__ __forceinline__ float dot2(unsigned int w, unsigned int h, float acc) {
#if __has_builtin(__builtin_amdgcn_fdot2)
    return __builtin_amdgcn_fdot2(__builtin_bit_cast(half2_t, w),
                                  __builtin_bit_cast(half2_t, h), acc, false);
#else
    half2_t wv = __builtin_bit_cast(half2_t, w), hv = __builtin_bit_cast(half2_t, h);
    return acc + (float)wv.x * (float)hv.x + (float)wv.y * (float)hv.y;
#endif
}

__device__ __forceinline__ unsigned int bcast(unsigned int v, int lane) {
#if __has_builtin(__builtin_amdgcn_readlane)
    return __builtin_amdgcn_readlane(v, lane);   // -> SGPR, uniform
#else
    return __shfl((int)v, lane, 64);
#endif
}

// Bank-balanced padded index (multiple-of-4 pad keeps 16 B alignment; float4
// blocks at 8*lane never straddle a 32-float pad group).
__device__ __forceinline__ int pidx(int row) { return row + ((row >> 5) << 2); }

__device__ __forceinline__ float fast_tanh(float s) {
    // tanh(s) = 1 - 2/(e^{2s}+1); exp2(s*2*log2e). Exact at +/-inf.
#if __has_builtin(__builtin_amdgcn_exp2f)
    float e = __builtin_amdgcn_exp2f(s * 2.885390081777927f);
#else
    float e = __expf(2.0f * s);
#endif
    return 1.0f - 2.0f / (e + 1.0f);
}

__global__ __attribute__((amdgpu_flat_work_group_size(NTHREADS, NTHREADS)))
           __attribute__((amdgpu_waves_per_eu(2, 2)))
void rnn_persist(
    const float* __restrict__ x, const float* __restrict__ h_init,
    const float* __restrict__ W_hx, const float* __restrict__ W_hh,
    const float* __restrict__ b_h, const float* __restrict__ W_ph,
    const float* __restrict__ b_p, float* __restrict__ out)
{
    __shared__ uint4 Wl4[NW * RP * 64];        // 64 KB: pairs 28..31, b128/row
    __shared__ float part[2][NW][PSTRIDE];     // 36 KB: partials, dbuf, swizzled
    __shared__ float x_s[T_SEQ];               //  4 KB

    const int tid  = threadIdx.x;
    const int b    = blockIdx.x;
    const int w    = tid >> 6;                 // wave = k-slice owner
    const int lane = tid & 63;
    const int p    = lane & 31;                // reduce: pair index within slice

    for (int i = tid; i < T_SEQ; i += NTHREADS) x_s[i] = x[(size_t)b * T_SEQ + i];

    // Reduce-phase ownership: lane handles rows R0=64w+2p, R1=R0+1 (upper
    // half-wave duplicates lower: same addresses -> LDS broadcast, free).
    const int   R0   = 64 * w + 2 * p;
    const float whx0 = W_hx[R0],     bh0 = b_h[R0];
    const float whx1 = W_hx[R0 + 1], bh1 = b_h[R0 + 1];
    const int   pi2  = pidx(2 * (32 * w + p)); // = pidx(R0): float2 read offset

    // Load W slice: rows 8*lane..8*lane+7, cols [64w, 64w+64).
    // Pairs 0..27 -> registers; pairs 28..31 -> Wl4 (one b128 per row).
    unsigned int wreg[RP][PREG];               // 224 regs (arch VGPR + AGPR)
    #pragma unroll
    for (int r = 0; r < RP; ++r) {
        const float4* row = (const float4*)(W_hh + (size_t)(RP * lane + r) * HID + 64 * w);
        #pragma unroll
        for (int q = 0; q < 7; ++q) {          // pairs 0..13
            float4 v = row[q];
            wreg[r][2 * q]     = pack2(v.x, v.y);
            wreg[r][2 * q + 1] = pack2(v.z, v.w);
        }
#if __has_builtin(__builtin_amdgcn_sched_barrier)
        __builtin_amdgcn_sched_barrier(0);
#endif
        #pragma unroll
        for (int q = 7; q < 14; ++q) {         // pairs 14..27
            float4 v = row[q];
            wreg[r][2 * q]     = pack2(v.x, v.y);
            wreg[r][2 * q + 1] = pack2(v.z, v.w);
        }
        float4 v14 = row[14], v15 = row[15];
        Wl4[(w * RP + r) * 64 + lane] =
            make_uint4(pack2(v14.x, v14.y), pack2(v14.z, v14.w),
                       pack2(v15.x, v15.y), pack2(v15.z, v15.w));
#if __has_builtin(__builtin_amdgcn_sched_barrier)
        __builtin_amdgcn_sched_barrier(0);     // keep init-phase pressure low
#endif
    }

    // Opaque identity pin: blocks rematerialization of the packed W values.
    #pragma unroll
    for (int r = 0; r < RP; ++r)
        #pragma unroll
        for (int q = 0; q < PREG; ++q)
            asm volatile("" : "+v"(wreg[r][q]));

    __syncthreads();

    // h state: lane p of wave w carries pair q=32w+p as hpack (f16x2); this is
    // exactly the lane that readlane(p) broadcasts from. No LDS h traffic.
    float h0 = h_init[R0], h1 = h_init[R0 + 1];
    unsigned int hpack = pack2(h0, h1);

    #pragma unroll 1
    for (int t = 0; t < T_SEQ; ++t) {
        const int buf = t & 1;
        const float xw = x_s[t];

        float acc[RP];
        #pragma unroll
        for (int r = 0; r < RP; ++r) acc[r] = 0.0f;

        // Pairs 0..27: W from regs, h pair broadcast via readlane -> SGPR.
        #pragma unroll
        for (int q = 0; q < PREG; ++q) {
            unsigned int hp = bcast(hpack, q);
            #pragma unroll
            for (int r = 0; r < RP; ++r) acc[r] = dot2(wreg[r][q], hp, acc[r]);
        }
        // Pairs 28..31: W from LDS, one conflict-free b128 per row.
        {
            unsigned int hh0 = bcast(hpack, 28), hh1 = bcast(hpack, 29),
                         hh2 = bcast(hpack, 30), hh3 = bcast(hpack, 31);
            #pragma unroll
            for (int r = 0; r < RP; ++r) {
                uint4 wq = Wl4[(w * RP + r) * 64 + lane];
                acc[r] = dot2(wq.x, hh0, acc[r]);
                acc[r] = dot2(wq.y, hh1, acc[r]);
                acc[r] = dot2(wq.z, hh2, acc[r]);
                acc[r] = dot2(wq.w, hh3, acc[r]);
            }
        }

        // Partials for rows 8*lane..8*lane+7, swizzled (bank-balanced b128).
        // Row pairs are contiguous -> doubles as pair-major float2 layout.
        *(float4*)&part[buf][w][pidx(RP * lane)]     = make_float4(acc[0], acc[1], acc[2], acc[3]);
        *(float4*)&part[buf][w][pidx(RP * lane + 4)] = make_float4(acc[4], acc[5], acc[6], acc[7]);

        __syncthreads();   // partials visible; dbuf => one barrier/step is safe

        // Pair-major reduce: lane reduces rows R0, R0+1 via 8 float2 reads
        // (32 distinct b64 addrs = 2 addrs/bank = free 2-way; upper half-wave
        // broadcasts). hpack forms in-lane -> no hs round-trip.
        float s0 = whx0 * xw + bh0;
        float s1 = whx1 * xw + bh1;
        #pragma unroll
        for (int j = 0; j < NW; ++j) {
            float2 pv = *(const float2*)&part[buf][j][pi2];
            s0 += pv.x;
            s1 += pv.y;
        }
        h0 = fast_tanh(s0);
        h1 = fast_tanh(s1);
        hpack = pack2(h0, h1);
    }

    // Epilogue: p_out = W_ph @ h_last + b_p (stage h_last f32 in x_s).
    __syncthreads();
    if (lane < 32) {
        x_s[R0]     = h0;
        x_s[R0 + 1] = h1;
    }
    __syncthreads();

    for (int c = w; c < NCLS; c += NW) {
        float s = 0.0f;
        #pragma unroll
        for (int j = 0; j < 8; ++j) {
            int r = lane + 64 * j;
            s += W_ph[c * HID + r] * x_s[r];
        }
        #pragma unroll
        for (int off = 32; off; off >>= 1) s += __shfl_down(s, off, 64);
        if (lane == 0) out[b * NCLS + c] = s + b_p[c];
    }
}

extern "C" void kernel_launch(void* const* d_in, const int* in_sizes, int n_in,
                              void* d_out, int out_size, void* d_ws, size_t ws_size,
                              hipStream_t stream) {
    const float* x      = (const float*)d_in[0];
    const float* h_init = (const float*)d_in[1];
    const float* W_hx   = (const float*)d_in[2];
    const float* W_hh   = (const float*)d_in[3];
    const float* b_h    = (const float*)d_in[4];
    const float* W_ph   = (const float*)d_in[5];
    const float* b_p    = (const float*)d_in[6];
    float* out = (float*)d_out;

    const int B = in_sizes[0] / T_SEQ;   // 256 batch columns -> 256 workgroups
    rnn_persist<<<B, NTHREADS, 0, stream>>>(x, h_init, W_hx, W_hh, b_h, W_ph, b_p, out);
}

// Round 13
// 1434.440 us; speedup vs baseline: 1.1427x; 1.1427x over previous
//
#include <hip/hip_runtime.h>

// VanillaRNN: h_{t+1} = tanh(W_hx x_t + W_hh h_t + b_h), T=1024, H=512, B=256.
// R13 = R9 restored verbatim (best: 1438 us). R10 (pk_fma), R11 (shfl
// h-exchange), R12 (pair-major float2 reduce) each regressed; this structure's
// budget: 3370 cyc/step = 2048 dot2-issue floor (512 dot2/SIMD @ ~4 cyc,
// fleet MAC bound) + ~550 necessary VALU (readlane/reduce/tanh) + ~775 serial
// stall (barrier + in-order LDS of a strictly serial recurrence).
// Design: 1 batch column/WG (256 WGs ~ 256 CUs), 512 thr = 8 waves (2/SIMD),
// wave w owns k-slice [64w,64w+64), lane owns 8 rows in the dot phase.
// W_hh f16: 28 pairs/row in regs (224; arch VGPR + AGPR via unified file),
// 4 pairs/row in LDS (one conflict-free b128/row/step). h: f16 ring in LDS,
// wave-internal (in-order DS, no barrier). Partials: swizzled f32, double-
// buffered, one barrier/step; reduce = thread tid owns row tid, 8 b32 reads.

#define T_SEQ    1024
#define HID      512
#define NTHREADS 512
#define NW       8            // waves
#define NCLS     10
#define RP       8            // rows per thread (dot phase)
#define PAIRS    32           // f16 pairs per wave k-slice (64 k)
#define PREG     28           // pairs 0..27 in VGPRs (224 regs)
#define PSTRIDE  576          // padded part row: 512 + 16*4 pad, 16B-aligned

typedef _Float16 half2_t __attribute__((ext_vector_type(2)));

__device__ __forceinline__ unsigned int pack2(float a, float b) {
    half2_t h = {(_Float16)a, (_Float16)b};
    return __builtin_bit_cast(unsigned int, h);
}

__device__ __forceinline__ float dot2(unsigned int w, unsigned int h, float acc) {
#if __has_builtin(__builtin_amdgcn_fdot2)
    return __builtin_amdgcn_fdot2(__builtin_bit_cast(half2_t, w),
                                  __builtin_bit_cast(half2_t, h), acc, false);
#else
    half2_t wv = __builtin_bit_cast(half2_t, w), hv = __builtin_bit_cast(half2_t, h);
    return acc + (float)wv.x * (float)hv.x + (float)wv.y * (float)hv.y;
#endif
}

__device__ __forceinline__ unsigned int bcast(unsigned int v, int lane) {
#if __has_builtin(__builtin_amdgcn_readlane)
    return __builtin_amdgcn_readlane(v, lane);   // -> SGPR, uniform
#else
    return __shfl((int)v, lane, 64);
#endif
}

// Bank-balanced padded index (multiple-of-4 pad keeps 16 B alignment).
__device__ __forceinline__ int pidx(int row) { return row + ((row >> 5) << 2); }

__device__ __forceinline__ float fast_tanh(float s) {
    // tanh(s) = 1 - 2/(e^{2s}+1); exp2(s*2*log2e). Exact at +/-inf.
#if __has_builtin(__builtin_amdgcn_exp2f)
    float e = __builtin_amdgcn_exp2f(s * 2.885390081777927f);
#else
    float e = __expf(2.0f * s);
#endif
    return 1.0f - 2.0f / (e + 1.0f);
}

__global__ __attribute__((amdgpu_flat_work_group_size(NTHREADS, NTHREADS)))
           __attribute__((amdgpu_waves_per_eu(2, 2)))
void rnn_persist(
    const float* __restrict__ x, const float* __restrict__ h_init,
    const float* __restrict__ W_hx, const float* __restrict__ W_hh,
    const float* __restrict__ b_h, const float* __restrict__ W_ph,
    const float* __restrict__ b_p, float* __restrict__ out)
{
    __shared__ uint4    Wl4[NW * RP * 64];     // 64 KB: pairs 28..31, b128/row
    __shared__ float    part[2][NW][PSTRIDE];  // 36 KB: partials, dbuf, swizzled
    __shared__ float    x_s[T_SEQ];            //  4 KB
    __shared__ _Float16 hs[HID];               //  1 KB: h ring, wave-internal

    const int tid  = threadIdx.x;
    const int b    = blockIdx.x;
    const int w    = tid >> 6;                 // wave = k-slice owner
    const int lane = tid & 63;

    for (int i = tid; i < T_SEQ; i += NTHREADS) x_s[i] = x[(size_t)b * T_SEQ + i];

    const float whx = W_hx[tid];               // reduce phase: thread owns row tid
    const float bh  = b_h[tid];
    const int   pi  = pidx(tid);               // loop-invariant part-read index
    hs[tid] = (_Float16)h_init[tid];

    // Load W slice: rows 8*lane..8*lane+7, cols [64w, 64w+64).
    // Pairs 0..27 -> registers (two half-row batches to cap init pressure);
    // pairs 28..31 -> Wl4 (one b128 per row per step).
    unsigned int wreg[RP][PREG];               // 224 regs (arch VGPR + AGPR)
    #pragma unroll
    for (int r = 0; r < RP; ++r) {
        const float4* row = (const float4*)(W_hh + (size_t)(RP * lane + r) * HID + 64 * w);
        #pragma unroll
        for (int q = 0; q < 7; ++q) {          // pairs 0..13
            float4 v = row[q];
            wreg[r][2 * q]     = pack2(v.x, v.y);
            wreg[r][2 * q + 1] = pack2(v.z, v.w);
        }
#if __has_builtin(__builtin_amdgcn_sched_barrier)
        __builtin_amdgcn_sched_barrier(0);
#endif
        #pragma unroll
        for (int q = 7; q < 14; ++q) {         // pairs 14..27
            float4 v = row[q];
            wreg[r][2 * q]     = pack2(v.x, v.y);
            wreg[r][2 * q + 1] = pack2(v.z, v.w);
        }
        float4 v14 = row[14], v15 = row[15];
        Wl4[(w * RP + r) * 64 + lane] =
            make_uint4(pack2(v14.x, v14.y), pack2(v14.z, v14.w),
                       pack2(v15.x, v15.y), pack2(v15.z, v15.w));
#if __has_builtin(__builtin_amdgcn_sched_barrier)
        __builtin_amdgcn_sched_barrier(0);     // keep init-phase pressure low
#endif
    }

    // Opaque identity pin: blocks rematerialization of the packed W values.
    #pragma unroll
    for (int r = 0; r < RP; ++r)
        #pragma unroll
        for (int p = 0; p < PREG; ++p)
            asm volatile("" : "+v"(wreg[r][p]));

    __syncthreads();

    const unsigned int* hs32 = (const unsigned int*)hs;  // pair view
    float hval = 0.0f;

    #pragma unroll 1
    for (int t = 0; t < T_SEQ; ++t) {
        const int buf = t & 1;
        const float xw = x_s[t];

        // Wave-internal h ring read: lane p holds pair p of this wave's slice.
        // (Written by this wave's own lanes last step -> in-order DS, no sync.)
        unsigned int hpack = hs32[w * 32 + (lane & 31)];

        float acc[RP];
        #pragma unroll
        for (int r = 0; r < RP; ++r) acc[r] = 0.0f;

        // Pairs 0..27: W from regs, h pair broadcast via readlane -> SGPR.
        #pragma unroll
        for (int p = 0; p < PREG; ++p) {
            unsigned int hp = bcast(hpack, p);
            #pragma unroll
            for (int r = 0; r < RP; ++r) acc[r] = dot2(wreg[r][p], hp, acc[r]);
        }
        // Pairs 28..31: W from LDS, one conflict-free b128 per row.
        {
            unsigned int hh0 = bcast(hpack, 28), hh1 = bcast(hpack, 29),
                         hh2 = bcast(hpack, 30), hh3 = bcast(hpack, 31);
            #pragma unroll
            for (int r = 0; r < RP; ++r) {
                uint4 wq = Wl4[(w * RP + r) * 64 + lane];
                acc[r] = dot2(wq.x, hh0, acc[r]);
                acc[r] = dot2(wq.y, hh1, acc[r]);
                acc[r] = dot2(wq.z, hh2, acc[r]);
                acc[r] = dot2(wq.w, hh3, acc[r]);
            }
        }

        // Partials for rows 8*lane..8*lane+7, swizzled (bank-balanced b128).
        *(float4*)&part[buf][w][pidx(RP * lane)]     = make_float4(acc[0], acc[1], acc[2], acc[3]);
        *(float4*)&part[buf][w][pidx(RP * lane + 4)] = make_float4(acc[4], acc[5], acc[6], acc[7]);

        __syncthreads();   // partials visible; dbuf => one barrier/step is safe

        // Reduce: thread tid owns row tid; unit-stride b32 reads, conflict-free.
        float s = whx * xw + bh;
        #pragma unroll
        for (int j = 0; j < NW; ++j) s += part[buf][j][pi];

        hval = fast_tanh(s);
        hs[tid] = (_Float16)hval;   // consumed only by this thread's own wave
    }

    // Epilogue: p = W_ph @ h_last + b_p (h_last f32 staged in x_s).
    __syncthreads();
    x_s[tid] = hval;
    __syncthreads();

    for (int c = w; c < NCLS; c += NW) {
        float s = 0.0f;
        #pragma unroll
        for (int j = 0; j < 8; ++j) {
            int r = lane + 64 * j;
            s += W_ph[c * HID + r] * x_s[r];
        }
        #pragma unroll
        for (int off = 32; off; off >>= 1) s += __shfl_down(s, off, 64);
        if (lane == 0) out[b * NCLS + c] = s + b_p[c];
    }
}

extern "C" void kernel_launch(void* const* d_in, const int* in_sizes, int n_in,
                              void* d_out, int out_size, void* d_ws, size_t ws_size,
                              hipStream_t stream) {
    const float* x      = (const float*)d_in[0];
    const float* h_init = (const float*)d_in[1];
    const float* W_hx   = (const float*)d_in[2];
    const float* W_hh   = (const float*)d_in[3];
    const float* b_h    = (const float*)d_in[4];
    const float* W_ph   = (const float*)d_in[5];
    const float* b_p    = (const float*)d_in[6];
    float* out = (float*)d_out;

    const int B = in_sizes[0] / T_SEQ;   // 256 batch columns -> 256 workgroups
    rnn_persist<<<B, NTHREADS, 0, stream>>>(x, h_init, W_hx, W_hh, b_h, W_ph, b_p, out);
}